// Round 10
// baseline (30968.030 us; speedup 1.0000x reference)
//
#include <hip/hip_runtime.h>
#include <float.h>

// Batched transducer greedy decode, B=32 T=1000 H=640 V=5000, fp32.
// Persistent kernel, 240 blocks x 512 thr.
// R10 = R9 (19.06ms) with BOTH tree grid-barriers replaced by direction-
// specific producer->consumer flags (the true dependences are narrower):
//  - F1[157]: logits publish partials -> drain -> F1[bid]=t+1. Only gate
//    blocks poll (each thread its 10 source tiles). Logits never wait.
//  - F2[80]: gate writes hT/joint -> drain -> F2[q]=t+1. Everyone polls all
//    80 at loop top (needs full state for step t).
//  - C_rd: each gate block bumps after STAGING hT (early in A, off the
//    critical path). Gate B polls C_rd >= 80*(t+1) before overwriting
//    hT/joint (the W-A-R hazard old bar1 covered). All other orderings are
//    transitive (publish follows stage; state-write follows all partials
//    which follow all logits stages).
// Cuts the per-step sync chain from 2 x ~4-RT tree barriers + 240-wide
// straggler coupling to ~2 flag hops with minimal dependence sets.
#define BB 32
#define TT 1000
#define HH 640
#define H4 2560
#define VV 5000
#define NLOG 157   // logits tiles, 32 cols each (last tile 8 valid)
#define NGATE 80   // gate blocks: 8 units x 4 gates each
#define NB   240

// workspace layout (float offsets)
#define O_JOINT 0        // jointT[j][b]  (640x32)   cross-block (sc1 path)
#define O_HT    20480    // hT[j][b]      (640x32)   cross-block (sc1 path)
#define O_PM    40960    // partial max    [157*32]  cross-block (sc1 path)
#define O_PS    46080    // partial sumexp [157*32]  cross-block (sc1 path)
#define O_PI    51200    // partial argmax [157*32] (int bits)    (sc1 path)
#define O_BAR   56320    // flags area: F1[157] @0, F2[80] @192, C_rd @288 (u32)
#define O_CT    56960    // initial c (640x32) — consumed once at kernel start
#define O_PNT   77440    // initial out_PN (640x32) — consumed once
#define O_XWXB  97920    // embed@Wx + b  (5000x2560), optional
#define XWXB_ELEMS ((size_t)VV * (size_t)H4)
#define O_WHP   (O_XWXB + 12800000)   // repacked Wh: [80][640][32], optional
#define WHP_ELEMS ((size_t)NGATE * HH * 32)

typedef unsigned int u32;
typedef unsigned long long u64;
typedef float vf4 __attribute__((ext_vector_type(4)));  // for nontemporal builtins

__device__ __forceinline__ float sigf(float x) { return 1.0f / (1.0f + expf(-x)); }

// ---- sc1 (MALL-coherent, L2-bypassing) scalar access helpers.
__device__ __forceinline__ float ldc1(const float* p) {
  u32 v = __hip_atomic_load((const u32*)p, __ATOMIC_RELAXED, __HIP_MEMORY_SCOPE_AGENT);
  return __uint_as_float(v);
}
__device__ __forceinline__ void stc1(float* p, float x) {
  __hip_atomic_store((u32*)p, __float_as_uint(x), __ATOMIC_RELAXED, __HIP_MEMORY_SCOPE_AGENT);
}
__device__ __forceinline__ u32 ldu(const u32* p) {
  return __hip_atomic_load(p, __ATOMIC_RELAXED, __HIP_MEMORY_SCOPE_AGENT);
}
__device__ __forceinline__ void stu(u32* p, u32 v) {
  __hip_atomic_store(p, v, __ATOMIC_RELAXED, __HIP_MEMORY_SCOPE_AGENT);
}

// ---- staged sc1 burst: 20480 floats global -> LDS, 10 dwordx4/thread, ONE vmcnt.
__device__ __forceinline__ void stage_sc1_full(float* dst, const float* src, int tid) {
  const float* p0 = src + 4 * (tid + 0 * 512);
  const float* p1 = src + 4 * (tid + 1 * 512);
  const float* p2 = src + 4 * (tid + 2 * 512);
  const float* p3 = src + 4 * (tid + 3 * 512);
  const float* p4 = src + 4 * (tid + 4 * 512);
  const float* p5 = src + 4 * (tid + 5 * 512);
  const float* p6 = src + 4 * (tid + 6 * 512);
  const float* p7 = src + 4 * (tid + 7 * 512);
  const float* p8 = src + 4 * (tid + 8 * 512);
  const float* p9 = src + 4 * (tid + 9 * 512);
  float4 a0, a1, a2, a3, a4, a5, a6, a7, a8, a9;
  asm volatile(
      "global_load_dwordx4 %0, %10, off sc0 sc1\n\t"
      "global_load_dwordx4 %1, %11, off sc0 sc1\n\t"
      "global_load_dwordx4 %2, %12, off sc0 sc1\n\t"
      "global_load_dwordx4 %3, %13, off sc0 sc1\n\t"
      "global_load_dwordx4 %4, %14, off sc0 sc1\n\t"
      "global_load_dwordx4 %5, %15, off sc0 sc1\n\t"
      "global_load_dwordx4 %6, %16, off sc0 sc1\n\t"
      "global_load_dwordx4 %7, %17, off sc0 sc1\n\t"
      "global_load_dwordx4 %8, %18, off sc0 sc1\n\t"
      "global_load_dwordx4 %9, %19, off sc0 sc1\n\t"
      "s_waitcnt vmcnt(0)"
      : "=&v"(a0), "=&v"(a1), "=&v"(a2), "=&v"(a3), "=&v"(a4),
        "=&v"(a5), "=&v"(a6), "=&v"(a7), "=&v"(a8), "=&v"(a9)
      : "v"(p0), "v"(p1), "v"(p2), "v"(p3), "v"(p4),
        "v"(p5), "v"(p6), "v"(p7), "v"(p8), "v"(p9)
      : "memory");
  float4* d4 = (float4*)dst;
  d4[tid + 0 * 512] = a0;
  d4[tid + 1 * 512] = a1;
  d4[tid + 2 * 512] = a2;
  d4[tid + 3 * 512] = a3;
  d4[tid + 4 * 512] = a4;
  d4[tid + 5 * 512] = a5;
  d4[tid + 6 * 512] = a6;
  d4[tid + 7 * 512] = a7;
  d4[tid + 8 * 512] = a8;
  d4[tid + 9 * 512] = a9;
}

// ---------------- precompute: xwxb[v][c] = sum_k embed[v][k]*Wx[k][c] + b[c]
__global__ __launch_bounds__(256) void precompute_k(const float* __restrict__ embed,
                                                    const float* __restrict__ Wx,
                                                    const float* __restrict__ bias,
                                                    float* __restrict__ xwxb) {
  __shared__ float embT[HH * 17];
  const int tid = threadIdx.x;
  const int v0 = blockIdx.y * 16;
  const int c0 = blockIdx.x * 256 + (tid & 63) * 4;
  const int vg = tid >> 6;
  for (int i = tid; i < 16 * 160; i += 256) {
    int vr = i / 160, kq = i - vr * 160;
    int v = v0 + vr; if (v >= VV) v = VV - 1;
    float4 e = *(const float4*)&embed[(size_t)v * HH + kq * 4];
    embT[(kq * 4 + 0) * 17 + vr] = e.x;
    embT[(kq * 4 + 1) * 17 + vr] = e.y;
    embT[(kq * 4 + 2) * 17 + vr] = e.z;
    embT[(kq * 4 + 3) * 17 + vr] = e.w;
  }
  __syncthreads();
  float acc[16];
#pragma unroll
  for (int i = 0; i < 16; ++i) acc[i] = 0.f;
#pragma unroll 4
  for (int k = 0; k < HH; ++k) {
    float4 wv = *(const float4*)&Wx[(size_t)k * H4 + c0];
#pragma unroll
    for (int i = 0; i < 4; ++i) {
      float e = embT[k * 17 + vg * 4 + i];
      acc[i * 4 + 0] += e * wv.x;
      acc[i * 4 + 1] += e * wv.y;
      acc[i * 4 + 2] += e * wv.z;
      acc[i * 4 + 3] += e * wv.w;
    }
  }
  float4 bv = *(const float4*)&bias[c0];
#pragma unroll
  for (int i = 0; i < 4; ++i) {
    int v = v0 + vg * 4 + i;
    if (v < VV) {
      float4 r;
      r.x = acc[i * 4 + 0] + bv.x; r.y = acc[i * 4 + 1] + bv.y;
      r.z = acc[i * 4 + 2] + bv.z; r.w = acc[i * 4 + 3] + bv.w;
      *(float4*)&xwxb[(size_t)v * H4 + c0] = r;
    }
  }
}

// ---------------- repack Wh into dense per-gate-slice layout (once)
__global__ __launch_bounds__(256) void repack_k(const float* __restrict__ Wh,
                                                float* __restrict__ whp) {
  const int q = blockIdx.x;
  for (int i = threadIdx.x; i < HH * 32; i += 256) {
    int k = i >> 5, lc = i & 31;
    whp[((size_t)q * HH + k) * 32 + lc] =
        Wh[(size_t)k * H4 + (lc >> 3) * HH + q * 8 + (lc & 7)];
  }
}

// ---------------- init: flags zero + initial LSTM step (h0=c0=0, tok=0) + joint t=0
__global__ __launch_bounds__(256) void init_k(const float* __restrict__ tn,
                                              const float* __restrict__ embed,
                                              const float* __restrict__ Wx,
                                              const float* __restrict__ bias,
                                              float* ws, int use_table) {
  const int tid = threadIdx.x, bid = blockIdx.x;
  const int b = tid & 31, c8 = tid >> 5;
  const int j = bid * 8 + c8;
  if (bid == 0) {
    u32* bar = (u32*)(ws + O_BAR);
    for (int i = tid; i < 17 * 32; i += 256) bar[i] = 0u;
  }
  const float* xwxb = ws + O_XWXB;
  float g4[4];
  if (use_table) {
#pragma unroll
    for (int g = 0; g < 4; ++g) g4[g] = xwxb[g * HH + j];  // token 0 row
  } else {
#pragma unroll
    for (int g = 0; g < 4; ++g) g4[g] = bias[g * HH + j];
#pragma unroll 4
    for (int k = 0; k < HH; ++k) {
      float xv = embed[k];  // token 0 row
#pragma unroll
      for (int g = 0; g < 4; ++g) g4[g] += xv * Wx[(size_t)k * H4 + g * HH + j];
    }
  }
  float c1 = sigf(g4[0]) * tanhf(g4[2]);
  float h1 = sigf(g4[3]) * tanhf(c1);
  ws[O_CT + j * 32 + b] = c1;
  ws[O_HT + j * 32 + b] = h1;
  ws[O_PNT + j * 32 + b] = h1;
  ws[O_JOINT + j * 32 + b] = tanhf(tn[(size_t)b * TT * HH + j] + h1);
}

// ---------------- persistent decode kernel
__global__ __launch_bounds__(512) void decode_k(const float* __restrict__ tn,
                                                const float* __restrict__ embed,
                                                const float* __restrict__ Wx,
                                                const float* __restrict__ bias,
                                                const float* __restrict__ Wh,
                                                const float* __restrict__ Wc,
                                                const float* __restrict__ bc,
                                                float* __restrict__ out,
                                                float* ws, int use_table, int use_pack) {
  __shared__ float joint_s[20480];  // 80 KB: full 640x32 joint/h tile (per step)
  __shared__ float smem[10800];     // overlay: part[8][1152] / reduce / B scratch
  __shared__ float hwh_s[1056];     // gate: hwh[lc(32) stride 33][b]  (persists A->B)
  __shared__ float c_s[256];        // gate: c state (LDS-resident)
  __shared__ float pn_s[256];       // gate: out_PN state
  __shared__ int s_tok[32];
  __shared__ int s_upd[32];
  __shared__ int s_ptok[32];
  __shared__ float s_scores[32];
  const int tid = threadIdx.x, bid = blockIdx.x;
  const bool is_log = (bid < NLOG);
  const bool is_gate = (bid >= NLOG) && (bid < NLOG + NGATE);
  if (!is_log && !is_gate) return;  // idle blocks exit (no barrier membership now)

  u32* F1  = (u32*)(ws + O_BAR);        // [157] partials-ready, value t+1
  u32* F2  = (u32*)(ws + O_BAR) + 192;  // [80]  state-ready,    value t+1
  u32* CRD = (u32*)(ws + O_BAR) + 288;  // hT read-count (80 per step)
  const float* xwxb = ws + O_XWXB;
  const int q = bid - NLOG;  // gate slice index

  if (tid < 32) { s_ptok[tid] = 0; s_scores[tid] = 0.f; }
  if (is_gate && tid < 256) {
    const int jj = tid >> 5, b = tid & 31;
    c_s[jj * 32 + b] = ws[O_CT + (q * 8 + jj) * 32 + b];
    pn_s[jj * 32 + b] = ws[O_PNT + (q * 8 + jj) * 32 + b];
  }
  __syncthreads();

  // ---- GEMM thread decomposition: 8 cols x 4 batches per thread, 16-way K split
  const int lane = tid & 63, wvv = tid >> 6;
  const int sub = lane >> 5;          // K-split parity
  const int cg  = lane & 3;           // 4 col-groups of 8 cols
  const int bg  = (lane >> 2) & 7;    // 8 batch-groups of 4
  const int kb  = (wvv * 2 + sub) * 40;  // this thread's 40-row K chunk
  const float* wbase;
  int wstride;
  if (is_log) {
    int c = bid * 32 + cg * 8;
    if (c > VV - 8) c = VV - 8;   // clamp (dup cols; masked at logits stage)
    wbase = Wc + (size_t)kb * VV + c;
    wstride = VV;
  } else if (use_pack) {
    wbase = ws + O_WHP + ((size_t)q * HH + kb) * 32 + cg * 8;  // dense 128B lines
    wstride = 32;
  } else {
    wbase = Wh + (size_t)kb * H4 + cg * HH + q * 8;
    wstride = H4;
  }
  const float* jb0 = joint_s + kb * 32 + bg * 4;

  for (int t = 0; t < TT; ++t) {
    // ---- wait: state (joint/hT) for step t fully published (80 gate flags)
    if (tid < NGATE) {
      while (ldu(F2 + tid) < (u32)t) __builtin_amdgcn_s_sleep(1);
    }
    __syncthreads();

    float tnv = 0.f;  // gate: tn[b][t+1][8q+jj], prefetched (held into phase B)
    if (is_gate && tid < 256 && t + 1 < TT)
      tnv = tn[((size_t)(tid & 31) * TT + (t + 1)) * HH + q * 8 + (tid >> 5)];

    // ================= phase A =================
    stage_sc1_full(joint_s, ws + (is_log ? O_JOINT : O_HT), tid);
    __syncthreads();
    if (is_gate && tid == 0)  // this block's hT read is complete (LDS-resident now)
      (void)__hip_atomic_fetch_add(CRD, 1u, __ATOMIC_RELAXED, __HIP_MEMORY_SCOPE_AGENT);

    float acc[32];  // acc[c*4+b]: 8 cols x 4 batches
#pragma unroll
    for (int i = 0; i < 32; ++i) acc[i] = 0.f;
    if (is_log) {
      const float* wp = wbase;
      const float* jp = jb0;
#pragma unroll 4
      for (int kk = 0; kk < 40; ++kk) {
        float4 w0 = *(const float4*)(wp);
        float4 w1 = *(const float4*)(wp + 4);
        float4 jv = *(const float4*)(jp);
        wp += wstride;
        jp += 32;
        acc[0]  += w0.x * jv.x; acc[1]  += w0.x * jv.y; acc[2]  += w0.x * jv.z; acc[3]  += w0.x * jv.w;
        acc[4]  += w0.y * jv.x; acc[5]  += w0.y * jv.y; acc[6]  += w0.y * jv.z; acc[7]  += w0.y * jv.w;
        acc[8]  += w0.z * jv.x; acc[9]  += w0.z * jv.y; acc[10] += w0.z * jv.z; acc[11] += w0.z * jv.w;
        acc[12] += w0.w * jv.x; acc[13] += w0.w * jv.y; acc[14] += w0.w * jv.z; acc[15] += w0.w * jv.w;
        acc[16] += w1.x * jv.x; acc[17] += w1.x * jv.y; acc[18] += w1.x * jv.z; acc[19] += w1.x * jv.w;
        acc[20] += w1.y * jv.x; acc[21] += w1.y * jv.y; acc[22] += w1.y * jv.z; acc[23] += w1.y * jv.w;
        acc[24] += w1.z * jv.x; acc[25] += w1.z * jv.y; acc[26] += w1.z * jv.z; acc[27] += w1.z * jv.w;
        acc[28] += w1.w * jv.x; acc[29] += w1.w * jv.y; acc[30] += w1.w * jv.z; acc[31] += w1.w * jv.w;
      }
    } else {
      // gate: weight stream single-use per step -> non-temporal (no L2 pollution)
      const float* wp = wbase;
      const float* jp = jb0;
#pragma unroll 4
      for (int kk = 0; kk < 40; ++kk) {
        vf4 w0 = __builtin_nontemporal_load((const vf4*)(wp));
        vf4 w1 = __builtin_nontemporal_load((const vf4*)(wp + 4));
        float4 jv = *(const float4*)(jp);
        wp += wstride;
        jp += 32;
        acc[0]  += w0.x * jv.x; acc[1]  += w0.x * jv.y; acc[2]  += w0.x * jv.z; acc[3]  += w0.x * jv.w;
        acc[4]  += w0.y * jv.x; acc[5]  += w0.y * jv.y; acc[6]  += w0.y * jv.z; acc[7]  += w0.y * jv.w;
        acc[8]  += w0.z * jv.x; acc[9]  += w0.z * jv.y; acc[10] += w0.z * jv.z; acc[11] += w0.z * jv.w;
        acc[12] += w0.w * jv.x; acc[13] += w0.w * jv.y; acc[14] += w0.w * jv.z; acc[15] += w0.w * jv.w;
        acc[16] += w1.x * jv.x; acc[17] += w1.x * jv.y; acc[18] += w1.x * jv.z; acc[19] += w1.x * jv.w;
        acc[20] += w1.y * jv.x; acc[21] += w1.y * jv.y; acc[22] += w1.y * jv.z; acc[23] += w1.y * jv.w;
        acc[24] += w1.z * jv.x; acc[25] += w1.z * jv.y; acc[26] += w1.z * jv.z; acc[27] += w1.z * jv.w;
        acc[28] += w1.w * jv.x; acc[29] += w1.w * jv.y; acc[30] += w1.w * jv.z; acc[31] += w1.w * jv.w;
      }
    }
    // combine K-split pairs (sub 0/1) within the wave
#pragma unroll
    for (int i = 0; i < 32; ++i) acc[i] += __shfl_xor(acc[i], 32);
    float* part = smem;  // [8 waves][32 cols * 36]
    if (sub == 0) {
      float* pb = part + wvv * 1152 + bg * 4;
#pragma unroll
      for (int c = 0; c < 8; ++c)
        *(float4*)&pb[(cg * 8 + c) * 36] =
            make_float4(acc[c * 4 + 0], acc[c * 4 + 1], acc[c * 4 + 2], acc[c * 4 + 3]);
    }
    __syncthreads();

    const int b = tid & 31, colg = tid >> 5;
    if (is_log) {
      float* lm = smem + 9216;
      float* lsv = smem + 9744;
      int* lix = (int*)(smem + 10272);
      float m = -FLT_MAX; int ix = 0;
      float lv[2];
#pragma unroll
      for (int i = 0; i < 2; ++i) {
        const int cl = colg * 2 + i;
        float s = 0.f;
#pragma unroll
        for (int qq = 0; qq < 8; ++qq) s += part[qq * 1152 + cl * 36 + b];
        int cgl = bid * 32 + cl;
        float l = (cgl < VV) ? s + bc[cgl] : -FLT_MAX;
        lv[i] = l;
        if (l > m) { m = l; ix = cgl; }
      }
      float e = 0.f;
      if (m > -FLT_MAX) {
#pragma unroll
        for (int i = 0; i < 2; ++i) e += expf(lv[i] - m);
      }
      lm[colg * 33 + b] = m; lsv[colg * 33 + b] = e; lix[colg * 33 + b] = ix;
      __syncthreads();
      if (tid < 32) {
        float m2 = lm[tid], s2 = lsv[tid]; int ix2 = lix[tid];
#pragma unroll
        for (int qq = 1; qq < 16; ++qq) {
          float M = lm[qq * 33 + tid], S = lsv[qq * 33 + tid]; int I = lix[qq * 33 + tid];
          if (M > m2) { s2 = s2 * expf(m2 - M) + S; m2 = M; ix2 = I; }
          else if (M > -FLT_MAX) { s2 += S * expf(M - m2); }
        }
        stc1(&ws[O_PM + bid * 32 + tid], m2);
        stc1(&ws[O_PS + bid * 32 + tid], s2);
        stc1(&ws[O_PI + bid * 32 + tid], __int_as_float(ix2));
      }
      __syncthreads();                 // all partial stc1 drained (pre-barrier vmcnt)
      if (tid == 0) stu(F1 + bid, (u32)(t + 1));  // publish partials-ready
      continue;  // logits: straight to next step's F2 wait
    }

    // gate: fold partials into hwh (stays in LDS)
#pragma unroll
    for (int i = 0; i < 2; ++i) {
      const int cl = colg * 2 + i;
      float s = 0.f;
#pragma unroll
      for (int qq = 0; qq < 8; ++qq) s += part[qq * 1152 + cl * 36 + b];
      hwh_s[cl * 33 + b] = s;
    }

    // ================= phase B (gate blocks only) =================
    __syncthreads();                // A's smem (part) usage done; reuse below
    float* rm = smem;               // [16*33]
    float* rs = smem + 528;
    int* ri = (int*)(smem + 1056);
    float* gmat = smem + 1584;      // [32*33]
    float* xl = smem + 2640;        // [32*161] fallback staging
    const int r = tid & 31, c16 = tid >> 5;
    {
      // wait for this thread's 10 source tiles' partials
      for (;;) {
        bool ok = true;
#pragma unroll
        for (int i = 0; i < 10; ++i) {
          int idx = c16 * 10 + i;
          if (idx < NLOG && ldu(F1 + idx) < (u32)(t + 1)) ok = false;
        }
        if (ok) break;
        __builtin_amdgcn_s_sleep(1);
      }
      // hoisted gather: all 30 sc1 loads issued before the combine (1 shot)
      float Ms[10], Ss[10]; int Is[10];
#pragma unroll
      for (int i = 0; i < 10; ++i) {
        int idx = c16 * 10 + i;
        bool v = (idx < NLOG);
        int ic = v ? idx : 0;
        Ms[i] = ldc1(&ws[O_PM + ic * 32 + r]);
        Ss[i] = ldc1(&ws[O_PS + ic * 32 + r]);
        Is[i] = __float_as_int(ldc1(&ws[O_PI + ic * 32 + r]));
        if (!v) { Ms[i] = -FLT_MAX; Ss[i] = 0.f; Is[i] = 0; }
      }
      float m = -FLT_MAX, s = 0.f; int ix = 0;
#pragma unroll
      for (int i = 0; i < 10; ++i) {
        if (Ms[i] > m) { s = s * expf(m - Ms[i]) + Ss[i]; m = Ms[i]; ix = Is[i]; }
        else if (Ms[i] > -FLT_MAX) { s += Ss[i] * expf(Ms[i] - m); }
      }
      rm[c16 * 33 + r] = m; rs[c16 * 33 + r] = s; ri[c16 * 33 + r] = ix;
    }
    __syncthreads();
    if (tid < 32) {
      float m = rm[tid], s = rs[tid]; int ix = ri[tid];
#pragma unroll
      for (int qq = 1; qq < 16; ++qq) {
        float M = rm[qq * 33 + tid], S = rs[qq * 33 + tid]; int I = ri[qq * 33 + tid];
        if (M > m) { s = s * expf(m - M) + S; m = M; ix = I; }
        else { s += S * expf(M - m); }
      }
      int pos = ix;
      int upd = (pos != 0) ? 1 : 0;
      int ntk = upd ? pos : s_ptok[tid];
      s_tok[tid] = ntk; s_upd[tid] = upd; s_ptok[tid] = ntk;
      if (bid == NLOG) {  // emitter
        float sc = s_scores[tid];
        if (upd) sc -= logf(s);
        s_scores[tid] = sc;
        out[BB + (size_t)tid * TT + t] = upd ? (float)pos : 0.0f;
        if (t == TT - 1) out[tid] = sc;
      }
    }
    __syncthreads();

    // gate pre-activations for the block's 32 strided cols
    float gv[2];
#pragma unroll
    for (int h = 0; h < 2; ++h) {
      int lc = (tid >> 5) + h * 16;
      int wcol = (lc >> 3) * HH + q * 8 + (lc & 7);
      float v = hwh_s[lc * 33 + b];
      if (use_table) v += __builtin_nontemporal_load(&xwxb[(size_t)s_tok[b] * H4 + wcol]);
      else v += bias[wcol];
      gv[h] = v;
    }
    if (!use_table) {
      for (int st = 0; st < 4; ++st) {
        const int k0 = st * 160;
        __syncthreads();
        for (int i = tid; i < 32 * 160; i += 512) {
          int bb = i / 160, kk = i - bb * 160;
          xl[bb * 161 + kk] = embed[(size_t)s_tok[bb] * HH + k0 + kk];
        }
        __syncthreads();
        for (int k = 0; k < 160; ++k) {
          float xv = xl[b * 161 + k];
#pragma unroll
          for (int h = 0; h < 2; ++h) {
            int lc = (tid >> 5) + h * 16;
            int wcol = (lc >> 3) * HH + q * 8 + (lc & 7);
            gv[h] += xv * Wx[(size_t)(k0 + k) * H4 + wcol];
          }
        }
      }
    }
#pragma unroll
    for (int h = 0; h < 2; ++h) {
      int lc = (tid >> 5) + h * 16;
      gmat[lc * 33 + b] = gv[h];
    }
    __syncthreads();
    // W-A-R guard: all 80 gate blocks must have STAGED hT(t) before we overwrite
    if (tid == 0) {
      while (ldu(CRD) < 80u * (u32)(t + 1)) __builtin_amdgcn_s_sleep(1);
    }
    __syncthreads();
    if (tid < 256) {
      const int jj = tid >> 5, b2 = tid & 31;
      float gi = gmat[(0 * 8 + jj) * 33 + b2];
      float gf = gmat[(1 * 8 + jj) * 33 + b2];
      float gg = gmat[(2 * 8 + jj) * 33 + b2];
      float go = gmat[(3 * 8 + jj) * 33 + b2];
      float cold = c_s[jj * 32 + b2];
      float c2 = sigf(gf) * cold + sigf(gi) * tanhf(gg);
      float h2 = sigf(go) * tanhf(c2);
      float pv;
      if (s_upd[b2]) {
        c_s[jj * 32 + b2] = c2;
        pn_s[jj * 32 + b2] = h2;
        stc1(&ws[O_HT + (q * 8 + jj) * 32 + b2], h2);   // sc1 write-through
        pv = h2;
      } else {
        pv = pn_s[jj * 32 + b2];
      }
      if (t + 1 < TT)
        stc1(&ws[O_JOINT + (q * 8 + jj) * 32 + b2], tanhf(tnv + pv));  // sc1
    }
    __syncthreads();                 // all state stc1 drained (pre-barrier vmcnt)
    if (tid == 0) stu(F2 + q, (u32)(t + 1));  // publish state-ready
  }
}

extern "C" void kernel_launch(void* const* d_in, const int* in_sizes, int n_in,
                              void* d_out, int out_size, void* d_ws, size_t ws_size,
                              hipStream_t stream) {
  const float* tn    = (const float*)d_in[0];
  const float* embed = (const float*)d_in[1];
  const float* Wx    = (const float*)d_in[2];
  const float* Wh    = (const float*)d_in[3];
  const float* bias  = (const float*)d_in[4];
  const float* Wc    = (const float*)d_in[5];
  const float* bc    = (const float*)d_in[6];
  float* out = (float*)d_out;
  float* ws  = (float*)d_ws;

  const size_t need_table = (size_t)(O_XWXB + XWXB_ELEMS) * sizeof(float);
  const size_t need_pack  = (size_t)(O_WHP + WHP_ELEMS) * sizeof(float);
  const int use_table = (ws_size >= need_table) ? 1 : 0;
  const int use_pack  = (ws_size >= need_pack) ? 1 : 0;

  if (use_table)
    hipLaunchKernelGGL(precompute_k, dim3(10, 313), dim3(256), 0, stream,
                       embed, Wx, bias, ws + O_XWXB);
  if (use_pack)
    hipLaunchKernelGGL(repack_k, dim3(NGATE), dim3(256), 0, stream, Wh, ws + O_WHP);
  hipLaunchKernelGGL(init_k, dim3(80), dim3(256), 0, stream, tn, embed, Wx, bias, ws, use_table);
  hipLaunchKernelGGL(decode_k, dim3(NB), dim3(512), 0, stream,
                     tn, embed, Wx, bias, Wh, Wc, bc, out, ws, use_table, use_pack);
}